// Round 1
// baseline (107.400 us; speedup 1.0000x reference)
//
#include <hip/hip_runtime.h>

// Problem constants (fixed by the reference setup)
#define B_ 128
#define N_ 65536
#define P_ 4096
#define T_ 32
#define D_ 2
#define K_ 4
#define S_ 8                      // slices per batch in the scan kernel
#define PAIRS_PER_BLOCK (P_ / S_) // 512
#define PAIRS_PER_WAVE (PAIRS_PER_BLOCK / 4) // 128

// ---------------------------------------------------------------------------
// Kernel 1: gather birth/death filtration values into an interleaved float2
// array ws_bd[B*P]. Coalesced on index reads; fun_value row (256 KB/batch)
// is L2-resident so the random gathers mostly hit L2.
// ---------------------------------------------------------------------------
__global__ __launch_bounds__(256) void gather_bd(
        const float* __restrict__ fun,
        const int* __restrict__ bidx,
        const int* __restrict__ didx,
        float2* __restrict__ bd) {
    int tid = blockIdx.x * 256 + threadIdx.x; // 0 .. B_*P_-1
    int batch = tid >> 12;                    // P_ == 4096
    const float* f = fun + (size_t)batch * N_;
    float b = f[bidx[tid]];
    float d = f[didx[tid]];
    bd[tid] = make_float2(b, d);
}

// ---------------------------------------------------------------------------
// Kernel 2: per (batch, slice) block of 256 threads (4 waves).
// Lane l of every wave owns combo (t = l&31, dim = l>>5) — 64 combos == wave64.
// Each wave scans 128 pairs; every pair read is shared by all 64 combos, so
// there is no per-pair cross-lane work at all. Top-4 kept sorted in registers
// via a min/max insert chain. Waves merge through LDS; wave 0 writes the
// per-slice partial top-4.
// ---------------------------------------------------------------------------
__global__ __launch_bounds__(256) void scan_top4(
        const float2* __restrict__ bd,
        const int* __restrict__ pdim,
        float* __restrict__ partial) {
    __shared__ float2 bdS[PAIRS_PER_BLOCK];
    __shared__ int    pdS[PAIRS_PER_BLOCK];
    __shared__ float  mrg[4][64][4];

    int batch = blockIdx.x;
    int slice = blockIdx.y;
    int tid   = threadIdx.x;
    int base  = batch * P_ + slice * PAIRS_PER_BLOCK;

    // cooperative stage: 512 pairs into LDS (coalesced)
    for (int i = tid; i < PAIRS_PER_BLOCK; i += 256) {
        bdS[i] = bd[base + i];
        pdS[i] = pdim[base + i];
    }
    __syncthreads();

    int lane  = tid & 63;
    int wave  = tid >> 6;
    int t     = lane & 31;
    int mydim = lane >> 5;
    float tf  = (float)(t + 1) * 0.03125f; // == tseq[t], exact in fp32

    float v0 = 0.f, v1 = 0.f, v2 = 0.f, v3 = 0.f;
    int p0 = wave * PAIRS_PER_WAVE;
    #pragma unroll 4
    for (int i = 0; i < PAIRS_PER_WAVE; ++i) {
        float2 bdv = bdS[p0 + i]; // wave-uniform address -> LDS broadcast
        int   pd   = pdS[p0 + i];
        float tv   = fminf(tf - bdv.x, bdv.y - tf);
        float val  = (pd == mydim) ? tv : 0.0f;
        val = fmaxf(val, 0.0f);
        // sorted-descending insert chain
        float x;
        x = fminf(v0, val); v0 = fmaxf(v0, val); val = x;
        x = fminf(v1, val); v1 = fmaxf(v1, val); val = x;
        x = fminf(v2, val); v2 = fmaxf(v2, val); val = x;
        v3 = fmaxf(v3, val);
    }

    mrg[wave][lane][0] = v0;
    mrg[wave][lane][1] = v1;
    mrg[wave][lane][2] = v2;
    mrg[wave][lane][3] = v3;
    __syncthreads();

    if (wave == 0) {
        float u0 = 0.f, u1 = 0.f, u2 = 0.f, u3 = 0.f;
        #pragma unroll
        for (int w = 0; w < 4; ++w) {
            #pragma unroll
            for (int k = 0; k < 4; ++k) {
                float val = mrg[w][lane][k];
                float x;
                x = fminf(u0, val); u0 = fmaxf(u0, val); val = x;
                x = fminf(u1, val); u1 = fmaxf(u1, val); val = x;
                x = fminf(u2, val); u2 = fmaxf(u2, val); val = x;
                u3 = fmaxf(u3, val);
            }
        }
        float* dst = partial + (((size_t)batch * S_ + slice) * 64 + lane) * 4;
        dst[0] = u0; dst[1] = u1; dst[2] = u2; dst[3] = u3;
    }
}

// ---------------------------------------------------------------------------
// Kernel 3: fold the 8 slice-partials per (batch, combo) into the final top-4.
// combo = dim*32 + t, so out index = batch*256 + combo*4 + k matches the
// reference [B, D, T, K] layout. Values written in descending order (top_k).
// ---------------------------------------------------------------------------
__global__ __launch_bounds__(256) void final_merge(
        const float* __restrict__ partial,
        float* __restrict__ out) {
    int tid = blockIdx.x * 256 + threadIdx.x; // 0 .. B_*64-1
    int batch = tid >> 6;
    int combo = tid & 63;
    float u0 = 0.f, u1 = 0.f, u2 = 0.f, u3 = 0.f;
    for (int s = 0; s < S_; ++s) {
        const float* src = partial + (((size_t)batch * S_ + s) * 64 + combo) * 4;
        #pragma unroll
        for (int k = 0; k < 4; ++k) {
            float val = src[k];
            float x;
            x = fminf(u0, val); u0 = fmaxf(u0, val); val = x;
            x = fminf(u1, val); u1 = fmaxf(u1, val); val = x;
            x = fminf(u2, val); u2 = fmaxf(u2, val); val = x;
            u3 = fmaxf(u3, val);
        }
    }
    float* dst = out + (size_t)tid * 4;
    dst[0] = u0; dst[1] = u1; dst[2] = u2; dst[3] = u3;
}

extern "C" void kernel_launch(void* const* d_in, const int* in_sizes, int n_in,
                              void* d_out, int out_size, void* d_ws, size_t ws_size,
                              hipStream_t stream) {
    const float* fun  = (const float*)d_in[0]; // [B, N] f32
    const int*   bidx = (const int*)d_in[1];   // [B, P] i32
    const int*   didx = (const int*)d_in[2];   // [B, P] i32
    const int*   pdim = (const int*)d_in[3];   // [B, P] i32
    float* out = (float*)d_out;                // [B, D, T, K] f32

    float2* bdw     = (float2*)d_ws;                         // B*P float2 = 4 MB
    float*  partial = (float*)d_ws + (size_t)B_ * P_ * 2;    // B*S*64*4 f32 = 1 MB

    gather_bd<<<(B_ * P_) / 256, 256, 0, stream>>>(fun, bidx, didx, bdw);

    dim3 g2(B_, S_);
    scan_top4<<<g2, 256, 0, stream>>>(bdw, pdim, partial);

    final_merge<<<(B_ * 64) / 256, 256, 0, stream>>>(partial, out);
}

// Round 2
// 89.608 us; speedup vs baseline: 1.1986x; 1.1986x over previous
//
#include <hip/hip_runtime.h>

// Problem constants (fixed by the reference setup)
#define B_ 128
#define N_ 65536
#define P_ 4096
#define T_ 32
#define D_ 2
#define K_ 4
#define S_ 8                       // slices per batch
#define PPB 512                    // pairs per block (P_/S_)

// sorted-descending top-4 insert chain (7 ops)
#define INS(v0, v1, v2, v3, val)                                  \
    {                                                             \
        float _x = fminf(v0, val); v0 = fmaxf(v0, val);           \
        float _y = fminf(v1, _x);  v1 = fmaxf(v1, _x);            \
        float _z = fminf(v2, _y);  v2 = fmaxf(v2, _y);            \
        v3 = fmaxf(v3, _z);                                       \
    }

// ---------------------------------------------------------------------------
// Fused kernel: each block owns (batch, slice) = 512 pairs.
//  1. gather b/d from fun (XCD-swizzled so one batch's blocks share an XCD;
//     16 batches x 256 KB = 4 MB = one XCD's L2)
//  2. partition pairs by homology dim into LDS (ballot ranks; order within a
//     dim segment is irrelevant for top-k). Odd segment ends get a sentinel
//     pair (4,-4) whose tent value is always negative.
//  3. scan: two same-dim pairs per wave iteration; lanes 0-31 evaluate pair j,
//     lanes 32-63 pair j+1, each half covering all 32 t values. No dim select.
//  4. shfl_xor(32) merge of even/odd halves, LDS merge of 4 waves, wave 0
//     writes the per-slice partial top-4 for all 64 (dim,t) combos.
// ---------------------------------------------------------------------------
__global__ __launch_bounds__(256) void fused_scan(
        const float* __restrict__ fun,
        const int* __restrict__ bidx,
        const int* __restrict__ didx,
        const int* __restrict__ pdim,
        float* __restrict__ partial) {
    __shared__ float2 bdS[PPB + 8];
    __shared__ int    cntS[8];
    __shared__ float  mrg[4][64][4];

    int bid   = blockIdx.x;               // 0..1023
    int xcd   = bid & 7;
    int seq   = bid >> 3;                 // 0..127
    int batch = xcd * 16 + (seq & 15);    // all 8 slices of a batch on one XCD
    int slice = seq >> 4;                 // 0..7

    int tid  = threadIdx.x;
    int lane = tid & 63;
    int wave = tid >> 6;
    int base = batch * P_ + slice * PPB;

    // --- gather (coalesced index reads; fun row is L2-resident) ---
    const float* f = fun + (size_t)batch * N_;
    int p0 = base + tid, p1 = base + 256 + tid;
    int pd0 = pdim[p0], pd1 = pdim[p1];
    float b0 = f[bidx[p0]], d0 = f[didx[p0]];
    float b1 = f[bidx[p1]], d1 = f[didx[p1]];

    // --- partition by dim: set s = wave*2+{0,1}, 64 pairs each ---
    unsigned long long bal0 = __ballot(pd0 == 0);
    unsigned long long bal1 = __ballot(pd1 == 0);
    if (lane == 0) {
        cntS[wave * 2]     = __popcll(bal0);
        cntS[wave * 2 + 1] = __popcll(bal1);
    }
    __syncthreads();

    int s0 = wave * 2, s1 = s0 + 1;
    int pre0_s0 = 0, pre1_s0 = 0, pre0_s1 = 0, pre1_s1 = 0, n0tot = 0;
    #pragma unroll
    for (int s = 0; s < 8; ++s) {
        int cs = cntS[s];
        if (s < s0) { pre0_s0 += cs; pre1_s0 += 64 - cs; }
        if (s < s1) { pre0_s1 += cs; pre1_s1 += 64 - cs; }
        n0tot += cs;
    }
    int n1tot = PPB - n0tot;
    int A   = (n0tot + 1) & ~1;           // dim0 segment padded length
    int n1p = (n1tot + 1) & ~1;           // dim1 segment padded length

    unsigned long long lmask = (1ull << lane) - 1ull;
    int r0 = __popcll(bal0 & lmask);
    int r1 = __popcll(bal1 & lmask);
    int dst0 = (pd0 == 0) ? (pre0_s0 + r0) : (A + pre1_s0 + (lane - r0));
    int dst1 = (pd1 == 0) ? (pre0_s1 + r1) : (A + pre1_s1 + (lane - r1));
    bdS[dst0] = make_float2(b0, d0);
    bdS[dst1] = make_float2(b1, d1);
    if (tid == 0 && (n0tot & 1)) bdS[n0tot]     = make_float2(4.f, -4.f);
    if (tid == 1 && (n1tot & 1)) bdS[A + n1tot] = make_float2(4.f, -4.f);
    __syncthreads();

    // --- scan: two same-dim pairs per wave iteration ---
    int half = lane >> 5;
    int t    = lane & 31;
    float tf = (float)(t + 1) * 0.03125f; // tseq[t], exact in fp32

    float a0 = 0.f, a1 = 0.f, a2 = 0.f, a3 = 0.f;  // dim0 partial top-4
    float c0 = 0.f, c1 = 0.f, c2 = 0.f, c3 = 0.f;  // dim1 partial top-4

    #pragma unroll 4
    for (int j = wave * 2; j < A; j += 8) {
        float2 p = bdS[j + half];
        float val = fminf(tf - p.x, p.y - tf);
        INS(a0, a1, a2, a3, val);
    }
    #pragma unroll 4
    for (int j = A + wave * 2; j < A + n1p; j += 8) {
        float2 p = bdS[j + half];
        float val = fminf(tf - p.x, p.y - tf);
        INS(c0, c1, c2, c3, val);
    }

    // --- even/odd half merge: partner lane l^32 holds same (t, dim) work ---
    float u0 = (half == 0) ? a0 : c0, w0 = (half == 0) ? c0 : a0;
    float u1 = (half == 0) ? a1 : c1, w1 = (half == 0) ? c1 : a1;
    float u2 = (half == 0) ? a2 : c2, w2 = (half == 0) ? c2 : a2;
    float u3 = (half == 0) ? a3 : c3, w3 = (half == 0) ? c3 : a3;
    float q;
    q = __shfl_xor(w0, 32); INS(u0, u1, u2, u3, q);
    q = __shfl_xor(w1, 32); INS(u0, u1, u2, u3, q);
    q = __shfl_xor(w2, 32); INS(u0, u1, u2, u3, q);
    q = __shfl_xor(w3, 32); INS(u0, u1, u2, u3, q);
    // lane l now holds top-4 for combo = l (dim = l>>5, t = l&31)

    mrg[wave][lane][0] = u0;
    mrg[wave][lane][1] = u1;
    mrg[wave][lane][2] = u2;
    mrg[wave][lane][3] = u3;
    __syncthreads();

    if (wave == 0) {
        float v0 = 0.f, v1 = 0.f, v2 = 0.f, v3 = 0.f;
        #pragma unroll
        for (int w = 0; w < 4; ++w) {
            #pragma unroll
            for (int k = 0; k < 4; ++k) {
                float val = mrg[w][lane][k];
                INS(v0, v1, v2, v3, val);
            }
        }
        float* dst = partial + (((size_t)batch * S_ + slice) * 64 + lane) * 4;
        dst[0] = v0; dst[1] = v1; dst[2] = v2; dst[3] = v3;
    }
}

// ---------------------------------------------------------------------------
// Fold the 8 slice-partials per (batch, combo) into the final top-4.
// out index = batch*256 + combo*4 + k matches reference [B, D, T, K].
// ---------------------------------------------------------------------------
__global__ __launch_bounds__(256) void final_merge(
        const float* __restrict__ partial,
        float* __restrict__ out) {
    int tid   = blockIdx.x * 256 + threadIdx.x; // 0 .. B_*64-1
    int batch = tid >> 6;
    int combo = tid & 63;
    float v0 = 0.f, v1 = 0.f, v2 = 0.f, v3 = 0.f;
    for (int s = 0; s < S_; ++s) {
        const float* src = partial + (((size_t)batch * S_ + s) * 64 + combo) * 4;
        #pragma unroll
        for (int k = 0; k < 4; ++k) {
            float val = src[k];
            INS(v0, v1, v2, v3, val);
        }
    }
    float* dst = out + (size_t)tid * 4;
    dst[0] = v0; dst[1] = v1; dst[2] = v2; dst[3] = v3;
}

extern "C" void kernel_launch(void* const* d_in, const int* in_sizes, int n_in,
                              void* d_out, int out_size, void* d_ws, size_t ws_size,
                              hipStream_t stream) {
    const float* fun  = (const float*)d_in[0]; // [B, N] f32
    const int*   bidx = (const int*)d_in[1];   // [B, P] i32
    const int*   didx = (const int*)d_in[2];   // [B, P] i32
    const int*   pdim = (const int*)d_in[3];   // [B, P] i32
    float* out = (float*)d_out;                // [B, D, T, K] f32

    float* partial = (float*)d_ws;             // B*S*64*4 f32 = 1 MB

    fused_scan<<<B_ * S_, 256, 0, stream>>>(fun, bidx, didx, pdim, partial);
    final_merge<<<(B_ * 64) / 256, 256, 0, stream>>>(partial, out);
}